// Round 1
// baseline (2872.480 us; speedup 1.0000x reference)
//
#include <hip/hip_runtime.h>
#include <hip/hip_bf16.h>
#include <math.h>

#define N_NODES 50000
#define N_EDGES 800000
#define IN_F 256
#define HF 256      // NUM_HEADS * OUT_FEATS
#define NHEAD 4
#define OF 64

// ---- order-preserving float<->uint encoding for atomicMax on floats ----
__device__ __forceinline__ unsigned enc_f32(float x) {
  unsigned b = __float_as_uint(x);
  return ((int)b < 0) ? ~b : (b | 0x80000000u);
}
__device__ __forceinline__ float dec_f32(unsigned u) {
  return (u & 0x80000000u) ? __uint_as_float(u & 0x7FFFFFFFu) : __uint_as_float(~u);
}

// ---- init: zero out + denom, set m to encoded -FLT_MAX ----
__global__ __launch_bounds__(256) void init_kernel(float4* __restrict__ out4, int n_out4,
                                                   float* __restrict__ denom,
                                                   unsigned* __restrict__ m_u, int nh_tot) {
  int stride = gridDim.x * blockDim.x;
  int i = blockIdx.x * blockDim.x + threadIdx.x;
  float4 z = {0.f, 0.f, 0.f, 0.f};
  for (int j = i; j < n_out4; j += stride) out4[j] = z;
  unsigned NEG = enc_f32(-3.402823466e38f);
  for (int j = i; j < nh_tot; j += stride) { denom[j] = 0.f; m_u[j] = NEG; }
}

// ---- fp32 tiled GEMM: C[M,256] = A[M,256] @ B[256,256] ----
#define BM 64
#define BN 64
#define BK 16
#define ASTR (BK + 4)   // 20 words: 80B row stride, 16B-aligned, conflict-light

__global__ __launch_bounds__(256) void gemm_ft(const float* __restrict__ A,
                                               const float* __restrict__ B,
                                               float* __restrict__ C, int M) {
  __shared__ float As[BM][ASTR];
  __shared__ float Bs[BK][BN];
  int tid = threadIdx.x;
  int brow = blockIdx.x * BM;
  int bcol = blockIdx.y * BN;
  int tr = tid >> 4, tc = tid & 15;        // 16x16 thread grid, 4x4 each
  int lar = tid >> 2;                      // As row 0..63
  int lac = (tid & 3) << 2;                // As col {0,4,8,12}
  int lbr = tid >> 4;                      // Bs row 0..15
  int lbc = (tid & 15) << 2;               // Bs col {0..60}
  float acc[4][4] = {};

  for (int k0 = 0; k0 < IN_F; k0 += BK) {
    float4 av;
    int gr = brow + lar;
    if (gr < M) av = *(const float4*)&A[(size_t)gr * IN_F + k0 + lac];
    else        av = float4{0.f, 0.f, 0.f, 0.f};
    *(float4*)&As[lar][lac] = av;
    float4 bv = *(const float4*)&B[(size_t)(k0 + lbr) * HF + bcol + lbc];
    *(float4*)&Bs[lbr][lbc] = bv;
    __syncthreads();
#pragma unroll
    for (int kk = 0; kk < BK; ++kk) {
      float a0 = As[tr * 4 + 0][kk];
      float a1 = As[tr * 4 + 1][kk];
      float a2 = As[tr * 4 + 2][kk];
      float a3 = As[tr * 4 + 3][kk];
      float4 b = *(float4*)&Bs[kk][tc * 4];
      acc[0][0] += a0 * b.x; acc[0][1] += a0 * b.y; acc[0][2] += a0 * b.z; acc[0][3] += a0 * b.w;
      acc[1][0] += a1 * b.x; acc[1][1] += a1 * b.y; acc[1][2] += a1 * b.z; acc[1][3] += a1 * b.w;
      acc[2][0] += a2 * b.x; acc[2][1] += a2 * b.y; acc[2][2] += a2 * b.z; acc[2][3] += a2 * b.w;
      acc[3][0] += a3 * b.x; acc[3][1] += a3 * b.y; acc[3][2] += a3 * b.z; acc[3][3] += a3 * b.w;
    }
    __syncthreads();
  }
#pragma unroll
  for (int i = 0; i < 4; ++i) {
    int gr = brow + tr * 4 + i;
    if (gr < M) {
      float4 v = {acc[i][0], acc[i][1], acc[i][2], acc[i][3]};
      *(float4*)&C[(size_t)gr * HF + bcol + tc * 4] = v;
    }
  }
}

// ---- per-node logits: el/er[n][h] = dot(ft[n][h*64:...], attn_{l,r}[h]) ----
__global__ __launch_bounds__(256) void node_logits(const float* __restrict__ ft,
                                                   const float* __restrict__ al,
                                                   const float* __restrict__ ar,
                                                   float* __restrict__ el,
                                                   float* __restrict__ er, int N) {
  int t = threadIdx.x;           // 256: wave index == head
  int h = t >> 6, f = t & 63;
  float wl = al[h * OF + f], wr = ar[h * OF + f];
  for (int n = blockIdx.x; n < N; n += gridDim.x) {
    float v = ft[(size_t)n * HF + t];
    float pl = v * wl, pr = v * wr;
#pragma unroll
    for (int off = 32; off > 0; off >>= 1) {
      pl += __shfl_xor(pl, off);
      pr += __shfl_xor(pr, off);
    }
    if (f == 0) { el[n * NHEAD + h] = pl; er[n * NHEAD + h] = pr; }
  }
}

// ---- edge logits + leakyrelu + segment-max(dst) ----
__global__ __launch_bounds__(256) void edge_logits(const int* __restrict__ src,
                                                   const int* __restrict__ dst,
                                                   const float* __restrict__ el,
                                                   const float* __restrict__ er,
                                                   float* __restrict__ ebuf,
                                                   unsigned* __restrict__ m_u, int E) {
  int stride = gridDim.x * blockDim.x;
  for (int i = blockIdx.x * blockDim.x + threadIdx.x; i < E * NHEAD; i += stride) {
    int e = i >> 2, h = i & 3;
    int s = src[e], d = dst[e];
    float x = el[s * NHEAD + h] + er[d * NHEAD + h];
    x = x > 0.f ? x : 0.2f * x;
    ebuf[i] = x;
    atomicMax(&m_u[d * NHEAD + h], enc_f32(x));
  }
}

// ---- exp(e - m[dst]) + segment-sum(dst) into denom ----
__global__ __launch_bounds__(256) void exp_denom(const int* __restrict__ dst,
                                                 float* __restrict__ ebuf,
                                                 const unsigned* __restrict__ m_u,
                                                 float* __restrict__ denom, int E) {
  int stride = gridDim.x * blockDim.x;
  for (int i = blockIdx.x * blockDim.x + threadIdx.x; i < E * NHEAD; i += stride) {
    int e = i >> 2, h = i & 3;
    int d = dst[e];
    float x = __expf(ebuf[i] - dec_f32(m_u[d * NHEAD + h]));
    ebuf[i] = x;
    atomicAdd(&denom[d * NHEAD + h], x);
  }
}

// ---- gather ft[src], weight by a, atomic scatter-add into out[dst] ----
// one wave per edge; lane handles float4 (c = lane*4, head = lane/16)
__global__ __launch_bounds__(256) void scatter_msg(const int* __restrict__ src,
                                                   const int* __restrict__ dst,
                                                   const float* __restrict__ ft,
                                                   const float* __restrict__ ex,
                                                   const float* __restrict__ denom,
                                                   float* __restrict__ out, int E) {
  int gtid = blockIdx.x * blockDim.x + threadIdx.x;
  int wave = gtid >> 6, lane = gtid & 63;
  int nw = (gridDim.x * blockDim.x) >> 6;
  int c = lane << 2, h = lane >> 4;
  for (int e = wave; e < E; e += nw) {
    int s = src[e], d = dst[e];
    float a = ex[(size_t)e * NHEAD + h] / denom[d * NHEAD + h];
    float4 v = *(const float4*)&ft[(size_t)s * HF + c];
    float* o = out + (size_t)d * HF + c;
    atomicAdd(o + 0, v.x * a);
    atomicAdd(o + 1, v.y * a);
    atomicAdd(o + 2, v.z * a);
    atomicAdd(o + 3, v.w * a);
  }
}

extern "C" void kernel_launch(void* const* d_in, const int* in_sizes, int n_in,
                              void* d_out, int out_size, void* d_ws, size_t ws_size,
                              hipStream_t stream) {
  const float* feat = (const float*)d_in[0];
  const int*   src  = (const int*)d_in[1];
  const int*   dst  = (const int*)d_in[2];
  const float* W    = (const float*)d_in[3];
  const float* al   = (const float*)d_in[4];
  const float* ar   = (const float*)d_in[5];
  float* out = (float*)d_out;

  char* ws = (char*)d_ws;
  float*    ft    = (float*)(ws);                 // 50000*256*4 = 51,200,000 B
  float*    ebuf  = (float*)(ws + 51200000);      // 800000*4*4  = 12,800,000 B
  float*    el    = (float*)(ws + 64000000);      //   800,000 B
  float*    er    = (float*)(ws + 64800000);      //   800,000 B
  float*    denom = (float*)(ws + 65600000);      //   800,000 B
  unsigned* m_u   = (unsigned*)(ws + 66400000);   //   800,000 B  (total 67.2 MB)

  init_kernel<<<2048, 256, 0, stream>>>((float4*)out, N_NODES * HF / 4, denom, m_u,
                                        N_NODES * NHEAD);
  dim3 ggrid((N_NODES + BM - 1) / BM, HF / BN);
  gemm_ft<<<ggrid, 256, 0, stream>>>(feat, W, ft, N_NODES);
  node_logits<<<2048, 256, 0, stream>>>(ft, al, ar, el, er, N_NODES);
  edge_logits<<<4096, 256, 0, stream>>>(src, dst, el, er, ebuf, m_u, N_EDGES);
  exp_denom<<<4096, 256, 0, stream>>>(dst, ebuf, m_u, denom, N_EDGES);
  scatter_msg<<<8192, 256, 0, stream>>>(src, dst, ft, ebuf, denom, out, N_EDGES);
}

// Round 2
// 498.662 us; speedup vs baseline: 5.7604x; 5.7604x over previous
//
#include <hip/hip_runtime.h>
#include <hip/hip_bf16.h>
#include <math.h>

#define N_NODES 50000
#define N_EDGES 800000
#define IN_F 256
#define HF 256      // NUM_HEADS * OUT_FEATS
#define NHEAD 4
#define OF 64

// ---- order-preserving float<->uint encoding for atomicMax on floats ----
__device__ __forceinline__ unsigned enc_f32(float x) {
  unsigned b = __float_as_uint(x);
  return ((int)b < 0) ? ~b : (b | 0x80000000u);
}
__device__ __forceinline__ float dec_f32(unsigned u) {
  return (u & 0x80000000u) ? __uint_as_float(u & 0x7FFFFFFFu) : __uint_as_float(~u);
}

// ---- init: denom=0, m=-inf(enc), deg=0 ----
__global__ __launch_bounds__(256) void init_kernel(float* __restrict__ denom,
                                                   unsigned* __restrict__ m_u, int nh_tot,
                                                   int* __restrict__ deg, int n) {
  int stride = gridDim.x * blockDim.x;
  int i = blockIdx.x * blockDim.x + threadIdx.x;
  unsigned NEG = enc_f32(-3.402823466e38f);
  for (int j = i; j < nh_tot; j += stride) { denom[j] = 0.f; m_u[j] = NEG; }
  for (int j = i; j < n; j += stride) deg[j] = 0;
}

// ---- fp32 tiled GEMM: C[M,256] = A[M,256] @ B[256,256] ----
#define BM 64
#define BN 64
#define BK 16
#define ASTR (BK + 4)

__global__ __launch_bounds__(256) void gemm_ft(const float* __restrict__ A,
                                               const float* __restrict__ B,
                                               float* __restrict__ C, int M) {
  __shared__ float As[BM][ASTR];
  __shared__ float Bs[BK][BN];
  int tid = threadIdx.x;
  int brow = blockIdx.x * BM;
  int bcol = blockIdx.y * BN;
  int tr = tid >> 4, tc = tid & 15;
  int lar = tid >> 2;
  int lac = (tid & 3) << 2;
  int lbr = tid >> 4;
  int lbc = (tid & 15) << 2;
  float acc[4][4] = {};

  for (int k0 = 0; k0 < IN_F; k0 += BK) {
    float4 av;
    int gr = brow + lar;
    if (gr < M) av = *(const float4*)&A[(size_t)gr * IN_F + k0 + lac];
    else        av = float4{0.f, 0.f, 0.f, 0.f};
    *(float4*)&As[lar][lac] = av;
    float4 bv = *(const float4*)&B[(size_t)(k0 + lbr) * HF + bcol + lbc];
    *(float4*)&Bs[lbr][lbc] = bv;
    __syncthreads();
#pragma unroll
    for (int kk = 0; kk < BK; ++kk) {
      float a0 = As[tr * 4 + 0][kk];
      float a1 = As[tr * 4 + 1][kk];
      float a2 = As[tr * 4 + 2][kk];
      float a3 = As[tr * 4 + 3][kk];
      float4 b = *(float4*)&Bs[kk][tc * 4];
      acc[0][0] += a0 * b.x; acc[0][1] += a0 * b.y; acc[0][2] += a0 * b.z; acc[0][3] += a0 * b.w;
      acc[1][0] += a1 * b.x; acc[1][1] += a1 * b.y; acc[1][2] += a1 * b.z; acc[1][3] += a1 * b.w;
      acc[2][0] += a2 * b.x; acc[2][1] += a2 * b.y; acc[2][2] += a2 * b.z; acc[2][3] += a2 * b.w;
      acc[3][0] += a3 * b.x; acc[3][1] += a3 * b.y; acc[3][2] += a3 * b.z; acc[3][3] += a3 * b.w;
    }
    __syncthreads();
  }
#pragma unroll
  for (int i = 0; i < 4; ++i) {
    int gr = brow + tr * 4 + i;
    if (gr < M) {
      float4 v = {acc[i][0], acc[i][1], acc[i][2], acc[i][3]};
      *(float4*)&C[(size_t)gr * HF + bcol + tc * 4] = v;
    }
  }
}

// ---- per-node logits ----
__global__ __launch_bounds__(256) void node_logits(const float* __restrict__ ft,
                                                   const float* __restrict__ al,
                                                   const float* __restrict__ ar,
                                                   float* __restrict__ el,
                                                   float* __restrict__ er, int N) {
  int t = threadIdx.x;
  int h = t >> 6, f = t & 63;
  float wl = al[h * OF + f], wr = ar[h * OF + f];
  for (int n = blockIdx.x; n < N; n += gridDim.x) {
    float v = ft[(size_t)n * HF + t];
    float pl = v * wl, pr = v * wr;
#pragma unroll
    for (int off = 32; off > 0; off >>= 1) {
      pl += __shfl_xor(pl, off);
      pr += __shfl_xor(pr, off);
    }
    if (f == 0) { el[n * NHEAD + h] = pl; er[n * NHEAD + h] = pr; }
  }
}

// ---- dst-degree histogram ----
__global__ __launch_bounds__(256) void count_kernel(const int* __restrict__ dst,
                                                    int* __restrict__ deg, int E) {
  int stride = gridDim.x * blockDim.x;
  for (int e = blockIdx.x * blockDim.x + threadIdx.x; e < E; e += stride)
    atomicAdd(&deg[dst[e]], 1);
}

// ---- single-block exclusive scan over deg -> row_start, cursor ----
__global__ __launch_bounds__(1024) void scan_kernel(const int* __restrict__ deg,
                                                    int* __restrict__ row_start,
                                                    int* __restrict__ cursor, int N) {
  __shared__ int sdata[1024];
  __shared__ int carry_s;
  int tid = threadIdx.x;
  if (tid == 0) carry_s = 0;
  __syncthreads();
  for (int base = 0; base < N; base += 1024) {
    int i = base + tid;
    int x = (i < N) ? deg[i] : 0;
    sdata[tid] = x;
    __syncthreads();
    for (int off = 1; off < 1024; off <<= 1) {
      int v = (tid >= off) ? sdata[tid - off] : 0;
      __syncthreads();
      sdata[tid] += v;
      __syncthreads();
    }
    int incl = sdata[tid];
    int excl = incl - x;
    int carry = carry_s;
    if (i < N) { int r = carry + excl; row_start[i] = r; cursor[i] = r; }
    __syncthreads();
    if (tid == 1023) carry_s = carry + incl;
    __syncthreads();
  }
  if (tid == 0) row_start[N] = carry_s;
}

// ---- edge logits + leakyrelu + segment-max(dst) ----
__global__ __launch_bounds__(256) void edge_logits(const int* __restrict__ src,
                                                   const int* __restrict__ dst,
                                                   const float* __restrict__ el,
                                                   const float* __restrict__ er,
                                                   float* __restrict__ ebuf,
                                                   unsigned* __restrict__ m_u, int E) {
  int stride = gridDim.x * blockDim.x;
  for (int i = blockIdx.x * blockDim.x + threadIdx.x; i < E * NHEAD; i += stride) {
    int e = i >> 2, h = i & 3;
    int s = src[e], d = dst[e];
    float x = el[s * NHEAD + h] + er[d * NHEAD + h];
    x = x > 0.f ? x : 0.2f * x;
    ebuf[i] = x;
    atomicMax(&m_u[d * NHEAD + h], enc_f32(x));
  }
}

// ---- exp(e - m[dst]) + segment-sum(dst) into denom ----
__global__ __launch_bounds__(256) void exp_denom(const int* __restrict__ dst,
                                                 float* __restrict__ ebuf,
                                                 const unsigned* __restrict__ m_u,
                                                 float* __restrict__ denom, int E) {
  int stride = gridDim.x * blockDim.x;
  for (int i = blockIdx.x * blockDim.x + threadIdx.x; i < E * NHEAD; i += stride) {
    int e = i >> 2, h = i & 3;
    int d = dst[e];
    float x = __expf(ebuf[i] - dec_f32(m_u[d * NHEAD + h]));
    ebuf[i] = x;
    atomicAdd(&denom[d * NHEAD + h], x);
  }
}

// ---- fill CSR: slot for each edge + precomputed alpha (4 heads) ----
__global__ __launch_bounds__(256) void fill_csr(const int* __restrict__ src,
                                                const int* __restrict__ dst,
                                                const float* __restrict__ ex,
                                                const float* __restrict__ denom,
                                                int* __restrict__ cursor,
                                                int* __restrict__ csr_src,
                                                float4* __restrict__ csr_a, int E) {
  int stride = gridDim.x * blockDim.x;
  for (int e = blockIdx.x * blockDim.x + threadIdx.x; e < E; e += stride) {
    int d = dst[e];
    int p = atomicAdd(&cursor[d], 1);
    csr_src[p] = src[e];
    float4 dn = *(const float4*)&denom[(size_t)d * NHEAD];
    float4 ev = *(const float4*)&ex[(size_t)e * NHEAD];
    csr_a[p] = float4{ev.x / dn.x, ev.y / dn.y, ev.z / dn.z, ev.w / dn.w};
  }
}

// ---- aggregate: one wave per dst node, register accumulation, one store ----
__global__ __launch_bounds__(256) void aggregate(const int* __restrict__ row_start,
                                                 const int* __restrict__ csr_src,
                                                 const float4* __restrict__ csr_a,
                                                 const float* __restrict__ ft,
                                                 float* __restrict__ out, int N) {
  int w = threadIdx.x >> 6, lane = threadIdx.x & 63;
  int n = blockIdx.x * 4 + w;
  if (n >= N) return;
  int h = lane >> 4;      // head for this lane's float4
  int c = lane << 2;      // column 0..252
  int j0 = row_start[n], j1 = row_start[n + 1];
  float4 acc0 = {0.f, 0.f, 0.f, 0.f};
  float4 acc1 = {0.f, 0.f, 0.f, 0.f};
  int j = j0;
  for (; j + 1 < j1; j += 2) {
    int s0 = csr_src[j], s1 = csr_src[j + 1];
    float a0 = ((const float*)&csr_a[j])[h];
    float a1 = ((const float*)&csr_a[j + 1])[h];
    float4 v0 = *(const float4*)&ft[(size_t)s0 * HF + c];
    float4 v1 = *(const float4*)&ft[(size_t)s1 * HF + c];
    acc0.x += v0.x * a0; acc0.y += v0.y * a0; acc0.z += v0.z * a0; acc0.w += v0.w * a0;
    acc1.x += v1.x * a1; acc1.y += v1.y * a1; acc1.z += v1.z * a1; acc1.w += v1.w * a1;
  }
  if (j < j1) {
    int s0 = csr_src[j];
    float a0 = ((const float*)&csr_a[j])[h];
    float4 v0 = *(const float4*)&ft[(size_t)s0 * HF + c];
    acc0.x += v0.x * a0; acc0.y += v0.y * a0; acc0.z += v0.z * a0; acc0.w += v0.w * a0;
  }
  float4 r = {acc0.x + acc1.x, acc0.y + acc1.y, acc0.z + acc1.z, acc0.w + acc1.w};
  *(float4*)&out[(size_t)n * HF + c] = r;
}

extern "C" void kernel_launch(void* const* d_in, const int* in_sizes, int n_in,
                              void* d_out, int out_size, void* d_ws, size_t ws_size,
                              hipStream_t stream) {
  const float* feat = (const float*)d_in[0];
  const int*   src  = (const int*)d_in[1];
  const int*   dst  = (const int*)d_in[2];
  const float* W    = (const float*)d_in[3];
  const float* al   = (const float*)d_in[4];
  const float* ar   = (const float*)d_in[5];
  float* out = (float*)d_out;

  char* ws = (char*)d_ws;
  float*    ft      = (float*)(ws);                  // 51,200,000 B
  float*    ebuf    = (float*)(ws + 51200000);       // 12,800,000 B
  float*    el      = (float*)(ws + 64000000);       //    800,000 B
  float*    er      = (float*)(ws + 64800000);       //    800,000 B
  float*    denom   = (float*)(ws + 65600000);       //    800,000 B
  unsigned* m_u     = (unsigned*)(ws + 66400000);    //    800,000 B
  int*      deg     = (int*)(ws + 67200000);         //    200,000 B
  int*      cursor  = (int*)(ws + 67400000);         //    200,000 B
  int*      rowst   = (int*)(ws + 67600000);         //    200,016 B (N+1)
  int*      csr_src = (int*)(ws + 67800016);         //  3,200,000 B
  float4*   csr_a   = (float4*)(ws + 71000016);      // 12,800,000 B -> 83.8 MB total

  init_kernel<<<1024, 256, 0, stream>>>(denom, m_u, N_NODES * NHEAD, deg, N_NODES);
  dim3 ggrid((N_NODES + BM - 1) / BM, HF / BN);
  gemm_ft<<<ggrid, 256, 0, stream>>>(feat, W, ft, N_NODES);
  count_kernel<<<2048, 256, 0, stream>>>(dst, deg, N_EDGES);
  scan_kernel<<<1, 1024, 0, stream>>>(deg, rowst, cursor, N_NODES);
  node_logits<<<2048, 256, 0, stream>>>(ft, al, ar, el, er, N_NODES);
  edge_logits<<<4096, 256, 0, stream>>>(src, dst, el, er, ebuf, m_u, N_EDGES);
  exp_denom<<<4096, 256, 0, stream>>>(dst, ebuf, m_u, denom, N_EDGES);
  fill_csr<<<2048, 256, 0, stream>>>(src, dst, ebuf, denom, cursor, csr_src, csr_a, N_EDGES);
  aggregate<<<(N_NODES + 3) / 4, 256, 0, stream>>>(rowst, csr_src, csr_a, ft, out, N_NODES);
}

// Round 4
// 390.744 us; speedup vs baseline: 7.3513x; 1.2762x over previous
//
#include <hip/hip_runtime.h>
#include <hip/hip_bf16.h>
#include <math.h>

#define N_NODES 50000
#define N_EDGES 800000
#define IN_F 256
#define HF 256      // NUM_HEADS * OUT_FEATS
#define NHEAD 4
#define OF 64
#define MPAD 50048  // 391 * 128
#define NPAD 50176  // 49 * 1024
#define NB 49       // scan blocks

typedef __attribute__((ext_vector_type(8))) short short8;
typedef __attribute__((ext_vector_type(4))) float f32x4;

// ---- explicit bf16 conversions (this ROCm's __hip_bfloat16 lacks .data) ----
__device__ __forceinline__ ushort f32_to_bf16(float x) {
  unsigned u = __float_as_uint(x);
  u += 0x7FFFu + ((u >> 16) & 1u);   // round-to-nearest-even
  return (ushort)(u >> 16);
}
__device__ __forceinline__ float bf16_to_f32(ushort v) {
  return __uint_as_float(((unsigned)v) << 16);
}

// async global->LDS, 16B per lane; LDS dest is wave-uniform base + lane*16
__device__ __forceinline__ void gload_lds16(const void* g, void* l) {
  __builtin_amdgcn_global_load_lds(
      (const __attribute__((address_space(1))) unsigned int*)g,
      (__attribute__((address_space(3))) unsigned int*)l, 16, 0, 0);
}

// ---- init: denom=0, deg=0 (padded) ----
__global__ __launch_bounds__(256) void init_kernel(float* __restrict__ denom,
                                                   int* __restrict__ deg) {
  int stride = gridDim.x * blockDim.x;
  int i = blockIdx.x * blockDim.x + threadIdx.x;
  for (int j = i; j < N_NODES * NHEAD; j += stride) denom[j] = 0.f;
  for (int j = i; j < NPAD; j += stride) deg[j] = 0;
}

// ---- convert feat -> bf16, W -> W^T bf16 ----
__global__ __launch_bounds__(256) void convert_kernel(const float* __restrict__ feat,
                                                      const float* __restrict__ W,
                                                      ushort* __restrict__ feat_bf,
                                                      ushort* __restrict__ WT) {
  int stride = gridDim.x * blockDim.x;
  int i = blockIdx.x * blockDim.x + threadIdx.x;
  int n4 = N_NODES * IN_F / 4;
  for (int j = i; j < n4; j += stride) {
    float4 v = ((const float4*)feat)[j];
    ushort4 o;
    o.x = f32_to_bf16(v.x); o.y = f32_to_bf16(v.y);
    o.z = f32_to_bf16(v.z); o.w = f32_to_bf16(v.w);
    ((ushort4*)feat_bf)[j] = o;
  }
  for (int j = i; j < IN_F * HF; j += stride) {
    int n = j >> 8, k = j & 255;                 // WT[n][k] = W[k][n]
    WT[j] = f32_to_bf16(W[k * HF + n]);
  }
}

// ---- bf16 MFMA GEMM: ft[MPAD,256] = feat_bf[M,256] @ WT^T ----
__global__ __launch_bounds__(256) void gemm_mfma(const ushort* __restrict__ A,
                                                 const ushort* __restrict__ BT,
                                                 ushort* __restrict__ C) {
  __shared__ char lds[16384];               // As 8KB | Bs 8KB
  char* As = lds;
  char* Bs = lds + 8192;
  int tid = threadIdx.x;
  int w = tid >> 6, lane = tid & 63;
  int brow = blockIdx.x * 128;
  int bcol = blockIdx.y * 128;
  int wr = w >> 1, wc = w & 1;
  f32x4 acc[4][4];
#pragma unroll
  for (int m = 0; m < 4; ++m)
#pragma unroll
    for (int n = 0; n < 4; ++n) acc[m][n] = (f32x4){0.f, 0.f, 0.f, 0.f};

  int rl = lane & 15, khalf = lane >> 4;
  for (int k0 = 0; k0 < IN_F; k0 += 32) {
#pragma unroll
    for (int part = 0; part < 2; ++part) {
      int ii = w * 2 + part;                 // staging instr 0..7
      int off = ii * 1024 + lane * 16;       // byte offset in 8KB tile
      int trow = off >> 6, inb = (off & 63) >> 1;  // tile row, element-in-row
      int ga = min(brow + trow, N_NODES - 1);
      gload_lds16(A + (size_t)ga * IN_F + k0 + inb, As + ii * 1024);
      gload_lds16(BT + (size_t)(bcol + trow) * IN_F + k0 + inb, Bs + ii * 1024);
    }
    __syncthreads();
    short8 a[4], b[4];
#pragma unroll
    for (int m = 0; m < 4; ++m)
      a[m] = *(const short8*)(As + (((wr * 64 + m * 16 + rl) << 6) | (khalf << 4)));
#pragma unroll
    for (int n = 0; n < 4; ++n)
      b[n] = *(const short8*)(Bs + (((wc * 64 + n * 16 + rl) << 6) | (khalf << 4)));
#pragma unroll
    for (int m = 0; m < 4; ++m)
#pragma unroll
      for (int n = 0; n < 4; ++n)
        acc[m][n] = __builtin_amdgcn_mfma_f32_16x16x32_bf16(a[m], b[n], acc[m][n], 0, 0, 0);
    __syncthreads();
  }
  // C/D layout: col = lane&15, row = (lane>>4)*4 + j   [m89-verified]
#pragma unroll
  for (int m = 0; m < 4; ++m) {
    int r0 = brow + wr * 64 + m * 16 + khalf * 4;
#pragma unroll
    for (int n = 0; n < 4; ++n) {
      int col = bcol + wc * 64 + n * 16 + rl;
#pragma unroll
      for (int j = 0; j < 4; ++j)
        C[(size_t)(r0 + j) * HF + col] = f32_to_bf16(acc[m][n][j]);
    }
  }
}

// ---- per-node logits from bf16 ft ----
__global__ __launch_bounds__(256) void node_logits(const ushort* __restrict__ ft,
                                                   const float* __restrict__ al,
                                                   const float* __restrict__ ar,
                                                   float* __restrict__ el,
                                                   float* __restrict__ er) {
  int t = threadIdx.x;
  int h = t >> 6, f = t & 63;
  float wl = al[h * OF + f], wr = ar[h * OF + f];
  for (int n = blockIdx.x; n < N_NODES; n += gridDim.x) {
    float v = bf16_to_f32(ft[(size_t)n * HF + t]);
    float pl = v * wl, pr = v * wr;
#pragma unroll
    for (int off = 32; off > 0; off >>= 1) {
      pl += __shfl_xor(pl, off);
      pr += __shfl_xor(pr, off);
    }
    if (f == 0) { el[n * NHEAD + h] = pl; er[n * NHEAD + h] = pr; }
  }
}

// ---- edge pass: logits + leakyrelu + exp + denom atomics + degree ----
__global__ __launch_bounds__(256) void edge_pass(const int* __restrict__ src,
                                                 const int* __restrict__ dst,
                                                 const float* __restrict__ el,
                                                 const float* __restrict__ er,
                                                 float4* __restrict__ ebuf,
                                                 float* __restrict__ denom,
                                                 int* __restrict__ deg) {
  int stride = gridDim.x * blockDim.x;
  for (int e = blockIdx.x * blockDim.x + threadIdx.x; e < N_EDGES; e += stride) {
    int s = src[e], d = dst[e];
    float4 l = *(const float4*)&el[(size_t)s * NHEAD];
    float4 r = *(const float4*)&er[(size_t)d * NHEAD];
    float x0 = l.x + r.x, x1 = l.y + r.y, x2 = l.z + r.z, x3 = l.w + r.w;
    x0 = x0 > 0.f ? x0 : 0.2f * x0;  x1 = x1 > 0.f ? x1 : 0.2f * x1;
    x2 = x2 > 0.f ? x2 : 0.2f * x2;  x3 = x3 > 0.f ? x3 : 0.2f * x3;
    float4 ex = {__expf(x0), __expf(x1), __expf(x2), __expf(x3)};
    ebuf[e] = ex;
    float* dn = &denom[(size_t)d * NHEAD];
    atomicAdd(dn + 0, ex.x); atomicAdd(dn + 1, ex.y);
    atomicAdd(dn + 2, ex.z); atomicAdd(dn + 3, ex.w);
    atomicAdd(&deg[d], 1);
  }
}

// ---- hierarchical scan: deg -> row_start (exclusive) ----
__global__ __launch_bounds__(256) void scan1(const int* __restrict__ deg,
                                             int* __restrict__ rowst,
                                             int* __restrict__ bsum) {
  __shared__ int wsum[4];
  int t = threadIdx.x, b = blockIdx.x;
  int lane = t & 63, wid = t >> 6;
  int i0 = b * 1024 + t * 4;
  int4 v = ((const int4*)deg)[i0 >> 2];
  int s = v.x + v.y + v.z + v.w;
  int incl = s;
#pragma unroll
  for (int off = 1; off < 64; off <<= 1) {
    int tmp = __shfl_up(incl, off);
    if (lane >= off) incl += tmp;
  }
  if (lane == 63) wsum[wid] = incl;
  __syncthreads();
  int woff = 0;
#pragma unroll
  for (int ww = 0; ww < 4; ++ww) if (ww < wid) woff += wsum[ww];
  int e0 = woff + incl - s;
  int4 o = {e0, e0 + v.x, e0 + v.x + v.y, e0 + v.x + v.y + v.z};
  ((int4*)rowst)[i0 >> 2] = o;
  if (t == 255) bsum[b] = woff + incl;
}

__global__ __launch_bounds__(64) void scan2(const int* __restrict__ bsum,
                                            int* __restrict__ boff) {
  int lane = threadIdx.x;
  int v = (lane < NB) ? bsum[lane] : 0;
  int incl = v;
#pragma unroll
  for (int off = 1; off < 64; off <<= 1) {
    int tmp = __shfl_up(incl, off);
    if (lane >= off) incl += tmp;
  }
  if (lane < NB) boff[lane] = incl - v;
}

__global__ __launch_bounds__(256) void scan3(int* __restrict__ rowst,
                                             int* __restrict__ cursor,
                                             const int* __restrict__ boff) {
  int t = threadIdx.x, b = blockIdx.x;
  int i0 = b * 1024 + t * 4;
  int4 r = ((const int4*)rowst)[i0 >> 2];
  int o = boff[b];
  r.x += o; r.y += o; r.z += o; r.w += o;
  ((int4*)rowst)[i0 >> 2] = r;
  ((int4*)cursor)[i0 >> 2] = r;
}

// ---- fill CSR: slot per edge + alpha ----
__global__ __launch_bounds__(256) void fill_csr(const int* __restrict__ src,
                                                const int* __restrict__ dst,
                                                const float4* __restrict__ ebuf,
                                                const float* __restrict__ denom,
                                                int* __restrict__ cursor,
                                                int* __restrict__ csr_src,
                                                float4* __restrict__ csr_a) {
  int stride = gridDim.x * blockDim.x;
  for (int e = blockIdx.x * blockDim.x + threadIdx.x; e < N_EDGES; e += stride) {
    int d = dst[e];
    int p = atomicAdd(&cursor[d], 1);
    csr_src[p] = src[e];
    float4 ev = ebuf[e];
    float4 dn = *(const float4*)&denom[(size_t)d * NHEAD];
    csr_a[p] = float4{ev.x / dn.x, ev.y / dn.y, ev.z / dn.z, ev.w / dn.w};
  }
}

// ---- aggregate: one wave per dst node; bf16 ft gather; single store ----
__global__ __launch_bounds__(256) void aggregate(const int* __restrict__ rowst,
                                                 const int* __restrict__ csr_src,
                                                 const float4* __restrict__ csr_a,
                                                 const ushort* __restrict__ ft,
                                                 float* __restrict__ out) {
  int w = threadIdx.x >> 6, lane = threadIdx.x & 63;
  int n = blockIdx.x * 4 + w;
  if (n >= N_NODES) return;
  int h = lane >> 4;      // head for this lane
  int c = lane << 2;      // column 0..252
  int j0 = rowst[n], j1 = rowst[n + 1];
  float a0x = 0.f, a0y = 0.f, a0z = 0.f, a0w = 0.f;
  float a1x = 0.f, a1y = 0.f, a1z = 0.f, a1w = 0.f;
  int j = j0;
  for (; j + 1 < j1; j += 2) {
    int s0 = csr_src[j], s1 = csr_src[j + 1];
    float a0 = ((const float*)&csr_a[j])[h];
    float a1 = ((const float*)&csr_a[j + 1])[h];
    uint2 u0 = *(const uint2*)(ft + (size_t)s0 * HF + c);
    uint2 u1 = *(const uint2*)(ft + (size_t)s1 * HF + c);
    a0x += __uint_as_float(u0.x << 16) * a0;
    a0y += __uint_as_float(u0.x & 0xFFFF0000u) * a0;
    a0z += __uint_as_float(u0.y << 16) * a0;
    a0w += __uint_as_float(u0.y & 0xFFFF0000u) * a0;
    a1x += __uint_as_float(u1.x << 16) * a1;
    a1y += __uint_as_float(u1.x & 0xFFFF0000u) * a1;
    a1z += __uint_as_float(u1.y << 16) * a1;
    a1w += __uint_as_float(u1.y & 0xFFFF0000u) * a1;
  }
  if (j < j1) {
    int s0 = csr_src[j];
    float a0 = ((const float*)&csr_a[j])[h];
    uint2 u0 = *(const uint2*)(ft + (size_t)s0 * HF + c);
    a0x += __uint_as_float(u0.x << 16) * a0;
    a0y += __uint_as_float(u0.x & 0xFFFF0000u) * a0;
    a0z += __uint_as_float(u0.y << 16) * a0;
    a0w += __uint_as_float(u0.y & 0xFFFF0000u) * a0;
  }
  float4 r = {a0x + a1x, a0y + a1y, a0z + a1z, a0w + a1w};
  *(float4*)&out[(size_t)n * HF + c] = r;
}

extern "C" void kernel_launch(void* const* d_in, const int* in_sizes, int n_in,
                              void* d_out, int out_size, void* d_ws, size_t ws_size,
                              hipStream_t stream) {
  const float* feat = (const float*)d_in[0];
  const int*   src  = (const int*)d_in[1];
  const int*   dst  = (const int*)d_in[2];
  const float* W    = (const float*)d_in[3];
  const float* al   = (const float*)d_in[4];
  const float* ar   = (const float*)d_in[5];
  float* out = (float*)d_out;

  char* ws = (char*)d_ws;
  ushort* ft_bf   = (ushort*)(ws);                    // 25,624,576 B (MPAD rows)
  ushort* feat_bf = (ushort*)(ws + 26000000);         // 25,600,000 B
  int*    csr_src = (int*)(ws + 26000000);            // aliased (after gemm)
  float4* csr_a   = (float4*)(ws + 29200000);         // aliased, 12.8MB
  ushort* WT      = (ushort*)(ws + 51600000);         //    131,072 B
  float4* ebuf    = (float4*)(ws + 51800000);         // 12,800,000 B
  float*  el      = (float*)(ws + 64600000);          //    800,000 B
  float*  er      = (float*)(ws + 65400000);          //    800,000 B
  float*  denom   = (float*)(ws + 66200000);          //    800,000 B
  int*    deg     = (int*)(ws + 67000000);            //    200,704 B (NPAD)
  int*    cursor  = (int*)(ws + 67200704);            //    200,704 B
  int*    rowst   = (int*)(ws + 67401408);            //    200,704 B
  int*    bsum    = (int*)(ws + 67602112);            //        196 B
  int*    boff    = (int*)(ws + 67602352);            //        196 B

  init_kernel<<<512, 256, 0, stream>>>(denom, deg);
  convert_kernel<<<2048, 256, 0, stream>>>(feat, W, feat_bf, WT);
  dim3 ggrid(MPAD / 128, HF / 128);
  gemm_mfma<<<ggrid, 256, 0, stream>>>(feat_bf, WT, ft_bf);
  node_logits<<<2048, 256, 0, stream>>>(ft_bf, al, ar, el, er);
  edge_pass<<<3125, 256, 0, stream>>>(src, dst, el, er, ebuf, denom, deg);
  scan1<<<NB, 256, 0, stream>>>(deg, rowst, bsum);
  scan2<<<1, 64, 0, stream>>>(bsum, boff);
  scan3<<<NB, 256, 0, stream>>>(rowst, cursor, boff);
  fill_csr<<<3125, 256, 0, stream>>>(src, dst, ebuf, denom, cursor, csr_src, csr_a);
  aggregate<<<(N_NODES + 3) / 4, 256, 0, stream>>>(rowst, csr_src, csr_a, ft_bf, out);
}

// Round 5
// 224.128 us; speedup vs baseline: 12.8162x; 1.7434x over previous
//
#include <hip/hip_runtime.h>
#include <hip/hip_bf16.h>
#include <math.h>

#define N_NODES 50000
#define N_EDGES 800000
#define IN_F 256
#define HF 256      // NUM_HEADS * OUT_FEATS
#define NHEAD 4
#define OF 64
#define MPAD 50048  // 391 * 128
#define NPAD 50176  // 49 * 1024
#define NB 49       // scan blocks

typedef __attribute__((ext_vector_type(8))) short short8;
typedef __attribute__((ext_vector_type(4))) float f32x4;

// ---- explicit bf16 conversions (this ROCm's __hip_bfloat16 lacks .data) ----
__device__ __forceinline__ ushort f32_to_bf16(float x) {
  unsigned u = __float_as_uint(x);
  u += 0x7FFFu + ((u >> 16) & 1u);   // round-to-nearest-even
  return (ushort)(u >> 16);
}

// async global->LDS, 16B per lane; LDS dest is wave-uniform base + lane*16
__device__ __forceinline__ void gload_lds16(const void* g, void* l) {
  __builtin_amdgcn_global_load_lds(
      (const __attribute__((address_space(1))) unsigned int*)g,
      (__attribute__((address_space(3))) unsigned int*)l, 16, 0, 0);
}

// ---- fused: feat->bf16, W->W^T bf16, dst degree histogram ----
__global__ __launch_bounds__(256) void convert_count(const float* __restrict__ feat,
                                                     const float* __restrict__ W,
                                                     const int* __restrict__ dst,
                                                     ushort* __restrict__ feat_bf,
                                                     ushort* __restrict__ WT,
                                                     int* __restrict__ deg) {
  int stride = gridDim.x * blockDim.x;
  int i = blockIdx.x * blockDim.x + threadIdx.x;
  int n4 = N_NODES * IN_F / 4;
  for (int j = i; j < n4; j += stride) {
    float4 v = ((const float4*)feat)[j];
    ushort4 o;
    o.x = f32_to_bf16(v.x); o.y = f32_to_bf16(v.y);
    o.z = f32_to_bf16(v.z); o.w = f32_to_bf16(v.w);
    ((ushort4*)feat_bf)[j] = o;
  }
  for (int j = i; j < IN_F * HF; j += stride) {
    int n = j >> 8, k = j & 255;                 // WT[n][k] = W[k][n]
    WT[j] = f32_to_bf16(W[k * HF + n]);
  }
  for (int e = i; e < N_EDGES; e += stride)
    atomicAdd(&deg[dst[e]], 1);
}

// ---- bf16 MFMA GEMM: ft[MPAD,256] = feat_bf[M,256] @ WT^T ----
__global__ __launch_bounds__(256) void gemm_mfma(const ushort* __restrict__ A,
                                                 const ushort* __restrict__ BT,
                                                 ushort* __restrict__ C) {
  __shared__ char lds[16384];               // As 8KB | Bs 8KB
  char* As = lds;
  char* Bs = lds + 8192;
  int tid = threadIdx.x;
  int w = tid >> 6, lane = tid & 63;
  int brow = blockIdx.x * 128;
  int bcol = blockIdx.y * 128;
  int wr = w >> 1, wc = w & 1;
  f32x4 acc[4][4];
#pragma unroll
  for (int m = 0; m < 4; ++m)
#pragma unroll
    for (int n = 0; n < 4; ++n) acc[m][n] = (f32x4){0.f, 0.f, 0.f, 0.f};

  int rl = lane & 15, khalf = lane >> 4;
  for (int k0 = 0; k0 < IN_F; k0 += 32) {
#pragma unroll
    for (int part = 0; part < 2; ++part) {
      int ii = w * 2 + part;                 // staging instr 0..7
      int off = ii * 1024 + lane * 16;       // byte offset in 8KB tile
      int trow = off >> 6, inb = (off & 63) >> 1;  // tile row, element-in-row
      int ga = min(brow + trow, N_NODES - 1);
      gload_lds16(A + (size_t)ga * IN_F + k0 + inb, As + ii * 1024);
      gload_lds16(BT + (size_t)(bcol + trow) * IN_F + k0 + inb, Bs + ii * 1024);
    }
    __syncthreads();
    short8 a[4], b[4];
#pragma unroll
    for (int m = 0; m < 4; ++m)
      a[m] = *(const short8*)(As + (((wr * 64 + m * 16 + rl) << 6) | (khalf << 4)));
#pragma unroll
    for (int n = 0; n < 4; ++n)
      b[n] = *(const short8*)(Bs + (((wc * 64 + n * 16 + rl) << 6) | (khalf << 4)));
#pragma unroll
    for (int m = 0; m < 4; ++m)
#pragma unroll
      for (int n = 0; n < 4; ++n)
        acc[m][n] = __builtin_amdgcn_mfma_f32_16x16x32_bf16(a[m], b[n], acc[m][n], 0, 0, 0);
    __syncthreads();
  }
  // C/D layout: col = lane&15, row = (lane>>4)*4 + j
#pragma unroll
  for (int m = 0; m < 4; ++m) {
    int r0 = brow + wr * 64 + m * 16 + khalf * 4;
#pragma unroll
    for (int n = 0; n < 4; ++n) {
      int col = bcol + wc * 64 + n * 16 + rl;
#pragma unroll
      for (int j = 0; j < 4; ++j)
        C[(size_t)(r0 + j) * HF + col] = f32_to_bf16(acc[m][n][j]);
    }
  }
}

// ---- per-node logits from bf16 ft ----
__global__ __launch_bounds__(256) void node_logits(const ushort* __restrict__ ft,
                                                   const float* __restrict__ al,
                                                   const float* __restrict__ ar,
                                                   float* __restrict__ el,
                                                   float* __restrict__ er) {
  int t = threadIdx.x;
  int h = t >> 6, f = t & 63;
  float wl = al[h * OF + f], wr = ar[h * OF + f];
  for (int n = blockIdx.x; n < N_NODES; n += gridDim.x) {
    float v = __uint_as_float(((unsigned)ft[(size_t)n * HF + t]) << 16);
    float pl = v * wl, pr = v * wr;
#pragma unroll
    for (int off = 32; off > 0; off >>= 1) {
      pl += __shfl_xor(pl, off);
      pr += __shfl_xor(pr, off);
    }
    if (f == 0) { el[n * NHEAD + h] = pl; er[n * NHEAD + h] = pr; }
  }
}

// ---- hierarchical scan: deg -> row_start (exclusive) ----
__global__ __launch_bounds__(256) void scan1(const int* __restrict__ deg,
                                             int* __restrict__ rowst,
                                             int* __restrict__ bsum) {
  __shared__ int wsum[4];
  int t = threadIdx.x, b = blockIdx.x;
  int lane = t & 63, wid = t >> 6;
  int i0 = b * 1024 + t * 4;
  int4 v = ((const int4*)deg)[i0 >> 2];
  int s = v.x + v.y + v.z + v.w;
  int incl = s;
#pragma unroll
  for (int off = 1; off < 64; off <<= 1) {
    int tmp = __shfl_up(incl, off);
    if (lane >= off) incl += tmp;
  }
  if (lane == 63) wsum[wid] = incl;
  __syncthreads();
  int woff = 0;
#pragma unroll
  for (int ww = 0; ww < 4; ++ww) if (ww < wid) woff += wsum[ww];
  int e0 = woff + incl - s;
  int4 o = {e0, e0 + v.x, e0 + v.x + v.y, e0 + v.x + v.y + v.z};
  ((int4*)rowst)[i0 >> 2] = o;
  if (t == 255) bsum[b] = woff + incl;
}

__global__ __launch_bounds__(64) void scan2(const int* __restrict__ bsum,
                                            int* __restrict__ boff) {
  int lane = threadIdx.x;
  int v = (lane < NB) ? bsum[lane] : 0;
  int incl = v;
#pragma unroll
  for (int off = 1; off < 64; off <<= 1) {
    int tmp = __shfl_up(incl, off);
    if (lane >= off) incl += tmp;
  }
  if (lane < NB) boff[lane] = incl - v;
}

__global__ __launch_bounds__(256) void scan3(int* __restrict__ rowst,
                                             int* __restrict__ cursor,
                                             const int* __restrict__ boff) {
  int t = threadIdx.x, b = blockIdx.x;
  int i0 = b * 1024 + t * 4;
  int4 r = ((const int4*)rowst)[i0 >> 2];
  int o = boff[b];
  r.x += o; r.y += o; r.z += o; r.w += o;
  ((int4*)rowst)[i0 >> 2] = r;
  ((int4*)cursor)[i0 >> 2] = r;
}

// ---- fused fill: edge logits + leakyrelu + exp + CSR scatter (raw exp) ----
__global__ __launch_bounds__(256) void fill_fused(const int* __restrict__ src,
                                                  const int* __restrict__ dst,
                                                  const float* __restrict__ el,
                                                  const float* __restrict__ er,
                                                  int* __restrict__ cursor,
                                                  int* __restrict__ csr_src,
                                                  float4* __restrict__ csr_a) {
  int stride = gridDim.x * blockDim.x;
  for (int e = blockIdx.x * blockDim.x + threadIdx.x; e < N_EDGES; e += stride) {
    int s = src[e], d = dst[e];
    float4 l = *(const float4*)&el[(size_t)s * NHEAD];
    float4 r = *(const float4*)&er[(size_t)d * NHEAD];
    float x0 = l.x + r.x, x1 = l.y + r.y, x2 = l.z + r.z, x3 = l.w + r.w;
    x0 = x0 > 0.f ? x0 : 0.2f * x0;  x1 = x1 > 0.f ? x1 : 0.2f * x1;
    x2 = x2 > 0.f ? x2 : 0.2f * x2;  x3 = x3 > 0.f ? x3 : 0.2f * x3;
    float4 ex = {__expf(x0), __expf(x1), __expf(x2), __expf(x3)};
    int p = atomicAdd(&cursor[d], 1);
    csr_src[p] = s;
    csr_a[p] = ex;
  }
}

// ---- aggregate: one wave per dst; in-register denom; single store ----
__global__ __launch_bounds__(256) void aggregate(const int* __restrict__ rowst,
                                                 const int* __restrict__ csr_src,
                                                 const float4* __restrict__ csr_a,
                                                 const ushort* __restrict__ ft,
                                                 float* __restrict__ out) {
  int w = threadIdx.x >> 6, lane = threadIdx.x & 63;
  int n = blockIdx.x * 4 + w;
  if (n >= N_NODES) return;
  int h = lane >> 4;      // head for this lane
  int c = lane << 2;      // column 0..252
  int j0 = rowst[n], j1 = rowst[n + 1];
  float a0x = 0.f, a0y = 0.f, a0z = 0.f, a0w = 0.f, den0 = 0.f;
  float a1x = 0.f, a1y = 0.f, a1z = 0.f, a1w = 0.f, den1 = 0.f;
  int j = j0;
  for (; j + 1 < j1; j += 2) {
    int s0 = csr_src[j], s1 = csr_src[j + 1];
    float a0 = ((const float*)&csr_a[j])[h];
    float a1 = ((const float*)&csr_a[j + 1])[h];
    uint2 u0 = *(const uint2*)(ft + (size_t)s0 * HF + c);
    uint2 u1 = *(const uint2*)(ft + (size_t)s1 * HF + c);
    den0 += a0; den1 += a1;
    a0x += __uint_as_float(u0.x << 16) * a0;
    a0y += __uint_as_float(u0.x & 0xFFFF0000u) * a0;
    a0z += __uint_as_float(u0.y << 16) * a0;
    a0w += __uint_as_float(u0.y & 0xFFFF0000u) * a0;
    a1x += __uint_as_float(u1.x << 16) * a1;
    a1y += __uint_as_float(u1.x & 0xFFFF0000u) * a1;
    a1z += __uint_as_float(u1.y << 16) * a1;
    a1w += __uint_as_float(u1.y & 0xFFFF0000u) * a1;
  }
  if (j < j1) {
    int s0 = csr_src[j];
    float a0 = ((const float*)&csr_a[j])[h];
    uint2 u0 = *(const uint2*)(ft + (size_t)s0 * HF + c);
    den0 += a0;
    a0x += __uint_as_float(u0.x << 16) * a0;
    a0y += __uint_as_float(u0.x & 0xFFFF0000u) * a0;
    a0z += __uint_as_float(u0.y << 16) * a0;
    a0w += __uint_as_float(u0.y & 0xFFFF0000u) * a0;
  }
  float den = den0 + den1;
  float inv = 1.0f / den;
  float4 r = {(a0x + a1x) * inv, (a0y + a1y) * inv, (a0z + a1z) * inv, (a0w + a1w) * inv};
  *(float4*)&out[(size_t)n * HF + c] = r;
}

extern "C" void kernel_launch(void* const* d_in, const int* in_sizes, int n_in,
                              void* d_out, int out_size, void* d_ws, size_t ws_size,
                              hipStream_t stream) {
  const float* feat = (const float*)d_in[0];
  const int*   src  = (const int*)d_in[1];
  const int*   dst  = (const int*)d_in[2];
  const float* W    = (const float*)d_in[3];
  const float* al   = (const float*)d_in[4];
  const float* ar   = (const float*)d_in[5];
  float* out = (float*)d_out;

  char* ws = (char*)d_ws;
  ushort* ft_bf   = (ushort*)(ws);                    // 25,624,576 B (MPAD rows)
  ushort* feat_bf = (ushort*)(ws + 26000000);         // 25,600,000 B
  int*    csr_src = (int*)(ws + 26000000);            // aliased (feat_bf dead after gemm)
  float4* csr_a   = (float4*)(ws + 29200000);         // aliased, 12.8 MB
  ushort* WT      = (ushort*)(ws + 51600000);         //    131,072 B
  float*  el      = (float*)(ws + 52000000);          //    800,000 B
  float*  er      = (float*)(ws + 52800000);          //    800,000 B
  int*    deg     = (int*)(ws + 53600000);            //    200,704 B (NPAD)
  int*    cursor  = (int*)(ws + 53800704);            //    200,704 B
  int*    rowst   = (int*)(ws + 54001408);            //    200,704 B
  int*    bsum    = (int*)(ws + 54202112);            //        196 B
  int*    boff    = (int*)(ws + 54202368);            //        196 B

  hipMemsetAsync(deg, 0, NPAD * sizeof(int), stream);
  convert_count<<<2048, 256, 0, stream>>>(feat, W, dst, feat_bf, WT, deg);
  dim3 ggrid(MPAD / 128, HF / 128);
  gemm_mfma<<<ggrid, 256, 0, stream>>>(feat_bf, WT, ft_bf);
  node_logits<<<2048, 256, 0, stream>>>(ft_bf, al, ar, el, er);
  scan1<<<NB, 256, 0, stream>>>(deg, rowst, bsum);
  scan2<<<1, 64, 0, stream>>>(bsum, boff);
  scan3<<<NB, 256, 0, stream>>>(rowst, cursor, boff);
  fill_fused<<<3125, 256, 0, stream>>>(src, dst, el, er, cursor, csr_src, csr_a);
  aggregate<<<(N_NODES + 3) / 4, 256, 0, stream>>>(rowst, csr_src, csr_a, ft_bf, out);
}